// Round 8
// baseline (125.063 us; speedup 1.0000x reference)
//
#include <hip/hip_runtime.h>

// ChamferLoss: B=4, N=M=8192, D=3, fp32. Scalar out.
// MFMA split-f16 (validated EXACT r6-r23): A = refs (LDS), B = queries (regs),
// in-lane min3 tree, VGPR-dest asm MFMA (r13), 4-fused issue group @ 4-wave
// band (r20).
// LEDGER: r0(2+2, 8-wave)=77.4 | r17 fence=149 | r18 presplit=80.1 |
// r19 presplit+gload_lds=82.8 | r20 4-fused @ (256,4)=75.5 (BEST) |
// r21 rotated pipeline=77.4 | r22 z=4 diag=91.6 (=> mfma ~16us, fills ~56us
// FIXED) | r23 SPAN=1024 B-frag-halving=75.9 (FLAT: prologue/barriers NOT
// the cost; reduce-traffic halving also didn't show).
// MODEL GAP: serial-sum model ~11us, overlapped ~7us, measured ~16us. A ~2x
// multiplier is unexplained, and the mfma kernel has NEVER produced rocprof
// counters (fills at ~41us occupy all top-5 slots at z<=4).
// r24 DIAGNOSTIC (committed in r23's guard; deliberately non-scoring):
// exact r20 kernel, gridDim.z=8, dir=z&1 -> 4 identical twins per direction
// writing bit-identical values (benign race; absmax must stay 0.0). mfma
// dispatch ~64us > fills -> top-1 WITH counters.
// Decision tree for r25 (z back to 2):
//   VALUBusy>=55 & MfmaUtil low  -> explicit v_min3_f32 tree (9 ops) on r20.
//   both<35 & occ~50%            -> latency-bound: QT=2, 8-wave band.
//   VGPR_Count>128               -> band wrong; trim live set.
//   LDS_BANK_CONFLICT >> 0       -> swizzle afrag.
//   FETCH >> ~100MB (z8)         -> input-path thrash; gload_lds coords.

#define BATCH   4
#define NPTS    8192
#define TPB     256
#define CSLICE  512                  // ref points per block (LDS slice)
#define QT      4                    // query tiles (32 cols) per wave
#define QBLK    (4 * QT * 32)        // 512 queries per block
#define MT      (CSLICE / 32)        // 16 ref tiles per slice
#define SLICES  (NPTS / CSLICE)      // 16
#define QBLKS   (NPTS / QBLK)        // 16

typedef _Float16 h8   __attribute__((ext_vector_type(8)));
typedef float    f16v __attribute__((ext_vector_type(16)));

__device__ __forceinline__ void split16(float v, _Float16& hi, _Float16& lo) {
    hi = (_Float16)v;
    lo = (_Float16)(v - (float)hi);
}

__device__ __forceinline__ float tree16(const f16v& d) {
    float g0 = fminf(fminf(d[0],  d[1]),  d[2]);
    float g1 = fminf(fminf(d[3],  d[4]),  d[5]);
    float g2 = fminf(fminf(d[6],  d[7]),  d[8]);
    float g3 = fminf(fminf(d[9],  d[10]), d[11]);
    float g4 = fminf(fminf(d[12], d[13]), d[14]);
    float h0 = fminf(fminf(g0, g1), d[15]);
    float h1 = fminf(fminf(g2, g3), g4);
    return fminf(h0, h1);
}

__global__ __launch_bounds__(TPB, 4) void chamfer_mfma(const float* __restrict__ xg,
                                                       const float* __restrict__ yg,
                                                       float* __restrict__ partial,
                                                       float* __restrict__ out) {
    __shared__ h8 afrag[CSLICE * 2];          // 16 KB, de-interleaved (conflict-free)

    const int tid    = threadIdx.x;
    const int qblock = blockIdx.x;            // [0,16)
    const int slice  = blockIdx.y & (SLICES - 1);
    const int b      = blockIdx.y >> 4;       // SLICES == 16
    const int dir    = blockIdx.z & 1;        // z in [0,8): 4 twins per direction
    const int lane   = tid & 63, wave = tid >> 6;
    const int col    = lane & 31, hv = lane >> 5;

    if (tid == 0) out[0] = 0.0f;              // benign identical-value race;
                                              // reduce runs after via stream order
    const float* q = dir ? yg : xg;           // query side (cols, register B-frags)
    const float* r = dir ? xg : yg;           // reference side (rows, LDS A-frags)

    // ---- stage ref A-frags: 2 points per thread, de-interleaved layout ----
    const float* rbase = r + ((size_t)b * NPTS + slice * CSLICE) * 3;
#pragma unroll
    for (int i = 0; i < CSLICE / TPB; ++i) {
        const int p = tid + i * TPB;
        float r0 = rbase[p * 3 + 0], r1 = rbase[p * 3 + 1], r2 = rbase[p * 3 + 2];
        _Float16 h0, l0, h1, l1, h2, l2, rnh, rnl;
        split16(r0, h0, l0);                  // a-side: RAW coords
        split16(r1, h1, l1);
        split16(r2, h2, l2);
        split16(fmaf(r0, r0, fmaf(r1, r1, r2 * r2)), rnh, rnl);
        const int base = (p >> 5) * 64 + (p & 31);            // [tile][hv][row]
        afrag[base]      = (h8){h0, h1, h2, l0, l1, l2, h0, h1};            // k0..7
        afrag[base + 32] = (h8){h2, rnh, rnl, (_Float16)1.0f, (_Float16)1.0f,
                                (_Float16)0.0f, (_Float16)0.0f, (_Float16)0.0f}; // k8..15
    }

    // ---- query B-frags: QT col-tiles per wave, resident in registers ----
    h8 bq[QT];
#pragma unroll
    for (int t = 0; t < QT; ++t) {
        const int qi = qblock * QBLK + (wave * QT + t) * 32 + col;
        const float* qp = q + ((size_t)b * NPTS + qi) * 3;
        float x0 = qp[0], x1 = qp[1], x2 = qp[2];
        _Float16 H0, L0, H1, L1, H2, L2, qnh, qnl;
        split16(-2.0f * x0, H0, L0);          // b-side: -2q, split AFTER scaling
        split16(-2.0f * x1, H1, L1);
        split16(-2.0f * x2, H2, L2);
        split16(fmaf(x0, x0, fmaf(x1, x1, x2 * x2)), qnh, qnl);
        h8 b0 = {H0, H1, H2, H0, H1, H2, L0, L1};                           // k0..7
        h8 b1 = {L2, (_Float16)1.0f, (_Float16)1.0f, qnh, qnl,
                 (_Float16)0.0f, (_Float16)0.0f, (_Float16)0.0f};           // k8..15
        bq[t] = hv ? b1 : b0;
    }
    __syncthreads();

    float cm[QT];
#pragma unroll
    for (int t = 0; t < QT; ++t) cm[t] = 3.0e38f;

    // ---- main loop: 1 A-frag read -> 4 MFMAs back-to-back, then 4 trees ----
    for (int mt = 0; mt < MT; ++mt) {
        const h8 ar = afrag[mt * 64 + lane];   // contiguous 16B/lane, conflict-free
        f16v d0, d1, d2, d3;
        asm("v_mfma_f32_32x32x16_f16 %0, %4, %5, 0\n\t"
            "v_mfma_f32_32x32x16_f16 %1, %4, %6, 0\n\t"
            "v_mfma_f32_32x32x16_f16 %2, %4, %7, 0\n\t"
            "v_mfma_f32_32x32x16_f16 %3, %4, %8, 0\n\t"
            "s_nop 7\n\t"
            "s_nop 7"
            : "=v"(d0), "=v"(d1), "=v"(d2), "=v"(d3)
            : "v"(ar), "v"(bq[0]), "v"(bq[1]), "v"(bq[2]), "v"(bq[3]));
        cm[0] = fminf(cm[0], tree16(d0));
        cm[1] = fminf(cm[1], tree16(d1));
        cm[2] = fminf(cm[2], tree16(d2));
        cm[3] = fminf(cm[3], tree16(d3));
    }

    // ---- epilogue: one xor32 per accumulator, coalesced stores ----
    // z-twins write identical values to identical addresses: benign.
    float* pp = partial + ((size_t)(dir * BATCH + b) * SLICES + slice) * NPTS
                        + qblock * QBLK;
#pragma unroll
    for (int t = 0; t < QT; ++t) {
        cm[t] = fminf(cm[t], __shfl_xor(cm[t], 32, 64));   // hv-partner rows
        if (hv == 0)
            pp[(wave * QT + t) * 32 + col] = cm[t];        // 32 lanes, 128B coalesced
    }
}

__global__ __launch_bounds__(TPB) void chamfer_reduce(const float* __restrict__ partial,
                                                      float* __restrict__ out) {
    const int tid = threadIdx.x;
    const int g   = blockIdx.x * TPB + tid;   // [0, 2*BATCH*NPTS)
    const int db  = g >> 13;                  // (dir*BATCH + b)
    const int n   = g & (NPTS - 1);

    const float* p = partial + (size_t)db * SLICES * NPTS + n;
    float v = 3.0e38f;
#pragma unroll
    for (int s = 0; s < SLICES; ++s)
        v = fminf(v, p[(size_t)s * NPTS]);    // coalesced across threads

    float w = v;
#pragma unroll
    for (int off = 32; off > 0; off >>= 1)
        w += __shfl_down(w, off, 64);
    __shared__ float ss[TPB / 64];
    if ((tid & 63) == 0) ss[tid >> 6] = w;
    __syncthreads();
    if (tid == 0)
        atomicAdd(out, (ss[0] + ss[1] + ss[2] + ss[3]) * (1.0f / (float)(BATCH * NPTS)));
}

extern "C" void kernel_launch(void* const* d_in, const int* in_sizes, int n_in,
                              void* d_out, int out_size, void* d_ws, size_t ws_size,
                              hipStream_t stream) {
    const float* x = (const float*)d_in[0];
    const float* y = (const float*)d_in[1];
    float* out = (float*)d_out;
    float* partial = (float*)d_ws;            // 2*4*16*8192*4 = 4 MB

    // DIAGNOSTIC: z=8 (4 identical twins per direction) to push chamfer_mfma
    // above the ~41us fills into rocprof top-5 with counters. r25 reverts z=2.
    chamfer_mfma<<<dim3(QBLKS, BATCH * SLICES, 8), TPB, 0, stream>>>(x, y, partial, out);
    chamfer_reduce<<<dim3(2 * BATCH * NPTS / TPB), TPB, 0, stream>>>(partial, out);
}

// Round 9
// 80.064 us; speedup vs baseline: 1.5620x; 1.5620x over previous
//
#include <hip/hip_runtime.h>

// ChamferLoss: B=4, N=M=8192, D=3, fp32. Scalar out.
// MFMA split-f16 (validated EXACT r6-r24): A = refs (LDS), B = queries (regs),
// in-lane min3 tree, VGPR-dest asm MFMA (r13), 2-fused + 2x s_nop7 hazard
// tail (r15-validated).
// LEDGER: r0(QT4 2+2, 8w)=77.4 | r17 fence=149 | r18 presplit=80.1 | r19
// +gload_lds=82.8 | r20 QT4 4-fused @4w=75.5 (BEST) | r21 rotate=77.4 |
// r22 z4 diag=91.6 | r23 SPAN1024=75.9 (prologue/barriers NOT the cost) |
// r24 z8 diag=125.1 -> COUNTERS: mfma 71.5us@z8, MfmaUtil 42%, VALUBusy 70%
// (INCLUDES mfma; pure VALU ~28% => min3 IS fused), Occ 46% (=4 waves/SIMD;
// VGPR_Count=44 is ARCH-only, d0-d3 live in 64 acc regs -> unified ~108),
// LDS_CONFLICT=0, HBM 1.3%. Matrix-pipe accounting closes (65.5k cyc/SIMD =
// 38% of 171.6k): duration is dependency bubbles (~30% idle issue).
// r25 (this): latency branch, exact reg math. QT=2 -> acc 32 + arch ~22 =
// ~54 unified <= 64 -> TRUE 8-wave band (launch_bounds(256,8)). Grid 32x64x2
// = 4096 blocks = 8 blocks/CU (LDS 8x16KB=128<=160). Chip-wide MFMA/VALU
// totals unchanged; occupancy 2x fills the bubbles. Per-mt: ds_read +
// 2-fused MFMA + 2x s_nop7 + 2 tree-folds (exact r15 pattern).
// Guards: absmax!=0 -> revert r20. dur>=75.5 or spill signature (FETCH/
// WRITE jump) -> r20 stands; structural floor ~66-68 (fill 40.6 + gaps ~10
// + mfma ~12 + reduce 3.5).

#define BATCH   4
#define NPTS    8192
#define TPB     256
#define CSLICE  512                  // ref points per block (LDS slice)
#define QT      2                    // query tiles (32 cols) per wave
#define QBLK    (4 * QT * 32)        // 256 queries per block
#define MT      (CSLICE / 32)        // 16 ref tiles per slice
#define SLICES  (NPTS / CSLICE)      // 16
#define QBLKS   (NPTS / QBLK)        // 32

typedef _Float16 h8   __attribute__((ext_vector_type(8)));
typedef float    f16v __attribute__((ext_vector_type(16)));

__device__ __forceinline__ void split16(float v, _Float16& hi, _Float16& lo) {
    hi = (_Float16)v;
    lo = (_Float16)(v - (float)hi);
}

__device__ __forceinline__ float tree16(const f16v& d) {
    float g0 = fminf(fminf(d[0],  d[1]),  d[2]);
    float g1 = fminf(fminf(d[3],  d[4]),  d[5]);
    float g2 = fminf(fminf(d[6],  d[7]),  d[8]);
    float g3 = fminf(fminf(d[9],  d[10]), d[11]);
    float g4 = fminf(fminf(d[12], d[13]), d[14]);
    float h0 = fminf(fminf(g0, g1), d[15]);
    float h1 = fminf(fminf(g2, g3), g4);
    return fminf(h0, h1);                 // caller folds cm -> min3 fuses
}

__global__ __launch_bounds__(TPB, 8) void chamfer_mfma(const float* __restrict__ xg,
                                                       const float* __restrict__ yg,
                                                       float* __restrict__ partial,
                                                       float* __restrict__ out) {
    __shared__ h8 afrag[CSLICE * 2];          // 16 KB, de-interleaved (conflict-free)

    const int tid    = threadIdx.x;
    const int qblock = blockIdx.x;            // [0,32)
    const int slice  = blockIdx.y & (SLICES - 1);
    const int b      = blockIdx.y >> 4;       // SLICES == 16
    const int dir    = blockIdx.z;
    const int lane   = tid & 63, wave = tid >> 6;
    const int col    = lane & 31, hv = lane >> 5;

    if (tid == 0) out[0] = 0.0f;              // benign identical-value race;
                                              // reduce runs after via stream order
    const float* q = dir ? yg : xg;           // query side (cols, register B-frags)
    const float* r = dir ? xg : yg;           // reference side (rows, LDS A-frags)

    // ---- stage ref A-frags: 2 points per thread, de-interleaved layout ----
    const float* rbase = r + ((size_t)b * NPTS + slice * CSLICE) * 3;
#pragma unroll
    for (int i = 0; i < CSLICE / TPB; ++i) {
        const int p = tid + i * TPB;
        float r0 = rbase[p * 3 + 0], r1 = rbase[p * 3 + 1], r2 = rbase[p * 3 + 2];
        _Float16 h0, l0, h1, l1, h2, l2, rnh, rnl;
        split16(r0, h0, l0);                  // a-side: RAW coords
        split16(r1, h1, l1);
        split16(r2, h2, l2);
        split16(fmaf(r0, r0, fmaf(r1, r1, r2 * r2)), rnh, rnl);
        const int base = (p >> 5) * 64 + (p & 31);            // [tile][hv][row]
        afrag[base]      = (h8){h0, h1, h2, l0, l1, l2, h0, h1};            // k0..7
        afrag[base + 32] = (h8){h2, rnh, rnl, (_Float16)1.0f, (_Float16)1.0f,
                                (_Float16)0.0f, (_Float16)0.0f, (_Float16)0.0f}; // k8..15
    }

    // ---- query B-frags: QT col-tiles per wave, resident in registers ----
    h8 bq[QT];
#pragma unroll
    for (int t = 0; t < QT; ++t) {
        const int qi = qblock * QBLK + (wave * QT + t) * 32 + col;
        const float* qp = q + ((size_t)b * NPTS + qi) * 3;
        float x0 = qp[0], x1 = qp[1], x2 = qp[2];
        _Float16 H0, L0, H1, L1, H2, L2, qnh, qnl;
        split16(-2.0f * x0, H0, L0);          // b-side: -2q, split AFTER scaling
        split16(-2.0f * x1, H1, L1);
        split16(-2.0f * x2, H2, L2);
        split16(fmaf(x0, x0, fmaf(x1, x1, x2 * x2)), qnh, qnl);
        h8 b0 = {H0, H1, H2, H0, H1, H2, L0, L1};                           // k0..7
        h8 b1 = {L2, (_Float16)1.0f, (_Float16)1.0f, qnh, qnl,
                 (_Float16)0.0f, (_Float16)0.0f, (_Float16)0.0f};           // k8..15
        bq[t] = hv ? b1 : b0;
    }
    __syncthreads();

    float cm[QT];
#pragma unroll
    for (int t = 0; t < QT; ++t) cm[t] = 3.0e38f;

    // ---- main loop: 1 A-frag read -> 2-fused MFMA + r15 nop tail -> 2 trees ----
    for (int mt = 0; mt < MT; ++mt) {
        const h8 ar = afrag[mt * 64 + lane];   // contiguous 16B/lane, conflict-free
        f16v d0, d1;
        asm("v_mfma_f32_32x32x16_f16 %0, %2, %3, 0\n\t"
            "v_mfma_f32_32x32x16_f16 %1, %2, %4, 0\n\t"
            "s_nop 7\n\t"
            "s_nop 7"
            : "=v"(d0), "=v"(d1)
            : "v"(ar), "v"(bq[0]), "v"(bq[1]));
        cm[0] = fminf(cm[0], tree16(d0));
        cm[1] = fminf(cm[1], tree16(d1));
    }

    // ---- epilogue: one xor32 per accumulator, coalesced stores ----
    float* pp = partial + ((size_t)(dir * BATCH + b) * SLICES + slice) * NPTS
                        + qblock * QBLK;
#pragma unroll
    for (int t = 0; t < QT; ++t) {
        cm[t] = fminf(cm[t], __shfl_xor(cm[t], 32, 64));   // hv-partner rows
        if (hv == 0)
            pp[(wave * QT + t) * 32 + col] = cm[t];        // 32 lanes, 128B coalesced
    }
}

__global__ __launch_bounds__(TPB) void chamfer_reduce(const float* __restrict__ partial,
                                                      float* __restrict__ out) {
    const int tid = threadIdx.x;
    const int g   = blockIdx.x * TPB + tid;   // [0, 2*BATCH*NPTS)
    const int db  = g >> 13;                  // (dir*BATCH + b)
    const int n   = g & (NPTS - 1);

    const float* p = partial + (size_t)db * SLICES * NPTS + n;
    float v = 3.0e38f;
#pragma unroll
    for (int s = 0; s < SLICES; ++s)
        v = fminf(v, p[(size_t)s * NPTS]);    // coalesced across threads

    float w = v;
#pragma unroll
    for (int off = 32; off > 0; off >>= 1)
        w += __shfl_down(w, off, 64);
    __shared__ float ss[TPB / 64];
    if ((tid & 63) == 0) ss[tid >> 6] = w;
    __syncthreads();
    if (tid == 0)
        atomicAdd(out, (ss[0] + ss[1] + ss[2] + ss[3]) * (1.0f / (float)(BATCH * NPTS)));
}

extern "C" void kernel_launch(void* const* d_in, const int* in_sizes, int n_in,
                              void* d_out, int out_size, void* d_ws, size_t ws_size,
                              hipStream_t stream) {
    const float* x = (const float*)d_in[0];
    const float* y = (const float*)d_in[1];
    float* out = (float*)d_out;
    float* partial = (float*)d_ws;            // 2*4*16*8192*4 = 4 MB

    chamfer_mfma<<<dim3(QBLKS, BATCH * SLICES, 2), TPB, 0, stream>>>(x, y, partial, out);
    chamfer_reduce<<<dim3(2 * BATCH * NPTS / TPB), TPB, 0, stream>>>(partial, out);
}